// Round 9
// baseline (387.434 us; speedup 1.0000x reference)
//
#include <hip/hip_runtime.h>
#include <math.h>

#define N_NODES 8192
#define N_EDGES 65536
#define F_IN    512
#define HID1    4096
#define HID2    1024
#define F_OUT   10
#define H3_STRIDE 16
#define W3B_STRIDE 1032   // padded K-stride of bf16 W3^T rows

typedef __bf16 bf16x8 __attribute__((ext_vector_type(8)));
typedef float floatx4 __attribute__((ext_vector_type(4)));
typedef float floatx16 __attribute__((ext_vector_type(16)));

static __device__ __forceinline__ unsigned short f2bf(float f) {
    union { float f; unsigned u; } v; v.f = f;
    unsigned r = v.u + 0x7fffu + ((v.u >> 16) & 1u);   // RNE
    return (unsigned short)(r >> 16);
}
static __device__ __forceinline__ float bf2f(unsigned short u) {
    union { unsigned u; float f; } v; v.u = ((unsigned)u) << 16;
    return v.f;
}
static __device__ __forceinline__ void unpack8(uint4 r, float* f) {
    union { unsigned u; float v; } c;
    c.u = r.x << 16;          f[0] = c.v;
    c.u = r.x & 0xffff0000u;  f[1] = c.v;
    c.u = r.y << 16;          f[2] = c.v;
    c.u = r.y & 0xffff0000u;  f[3] = c.v;
    c.u = r.z << 16;          f[4] = c.v;
    c.u = r.z & 0xffff0000u;  f[5] = c.v;
    c.u = r.w << 16;          f[6] = c.v;
    c.u = r.w & 0xffff0000u;  f[7] = c.v;
}
static __device__ __forceinline__ uint4 pack8(const float* f) {
    uint4 o;
    o.x = (unsigned)f2bf(f[0]) | ((unsigned)f2bf(f[1]) << 16);
    o.y = (unsigned)f2bf(f[2]) | ((unsigned)f2bf(f[3]) << 16);
    o.z = (unsigned)f2bf(f[4]) | ((unsigned)f2bf(f[5]) << 16);
    o.w = (unsigned)f2bf(f[6]) | ((unsigned)f2bf(f[7]) << 16);
    return o;
}

// ---------------------------------------------------------------------------
// hist+scan (one block): deg[] via LDS histogram, exclusive scan -> row_ptr,
// cnt[] zeroing.
// ---------------------------------------------------------------------------
__global__ __launch_bounds__(1024) void hist_scan_kernel(
        const int* __restrict__ ei, int* __restrict__ deg,
        int* __restrict__ row_ptr, int* __restrict__ cnt) {
    __shared__ int hist[N_NODES];        // 32 KB
    __shared__ int sums[1024];
    int t = threadIdx.x;
#pragma unroll
    for (int i = 0; i < 8; i++) hist[t + i * 1024] = 0;
    __syncthreads();
#pragma unroll
    for (int i = 0; i < 64; i++) {
        int d = ei[N_EDGES + i * 1024 + t];
        atomicAdd(&hist[d], 1);
    }
    __syncthreads();
    int base = t * 8;
    int local[8], run = 0;
#pragma unroll
    for (int i = 0; i < 8; i++) {
        int dv = hist[base + i];
        deg[base + i] = dv;
        cnt[base + i] = 0;
        local[i] = run; run += dv;
    }
    sums[t] = run;
    __syncthreads();
    for (int off = 1; off < 1024; off <<= 1) {
        int val = (t >= off) ? sums[t - off] : 0;
        __syncthreads();
        sums[t] += val;
        __syncthreads();
    }
    int offset = (t == 0) ? 0 : sums[t - 1];
#pragma unroll
    for (int i = 0; i < 8; i++) row_ptr[base + i] = offset + local[i];
    if (t == 1023) row_ptr[N_NODES] = sums[1023];
}

// ---------------------------------------------------------------------------
// megaprep: fill CSR (blocks 0..255) + xcvt (256..4351) + W1^T (4352..6399)
// + W2^T (6400..10495) + W3 bf16 cvt (10496). One launch.
// ---------------------------------------------------------------------------
static __device__ __forceinline__ void transpose_body(
        const float* __restrict__ W, unsigned short* __restrict__ Wt,
        int K, int N, int k0, int n0, int tid, float (*t)[33]) {
    int c = tid & 31, r8 = tid >> 5;
#pragma unroll
    for (int i = 0; i < 4; i++) {
        int r = r8 + i * 8;
        t[r][c] = W[(size_t)(k0 + r) * N + n0 + c];
    }
    __syncthreads();
#pragma unroll
    for (int i = 0; i < 4; i++) {
        int r = r8 + i * 8;
        Wt[(size_t)(n0 + r) * K + k0 + c] = f2bf(t[c][r]);
    }
}

__global__ __launch_bounds__(256) void megaprep_kernel(
        const int* __restrict__ ei, const int* __restrict__ deg,
        const int* __restrict__ row_ptr, int* __restrict__ cnt,
        int* __restrict__ csr_src, float* __restrict__ csr_w,
        const float* __restrict__ x, unsigned short* __restrict__ xb,
        const float* __restrict__ W1, unsigned short* __restrict__ W1t,
        const float* __restrict__ W2, unsigned short* __restrict__ W2t,
        const float* __restrict__ W3, unsigned short* __restrict__ w3b) {
    __shared__ float t[32][33];
    int b = blockIdx.x, tid = threadIdx.x;
    if (b < 256) {
        int e = b * 256 + tid;
        int s = ei[e];
        int d = ei[N_EDGES + e];
        int slot = row_ptr[d] + atomicAdd(&cnt[d], 1);
        csr_src[slot] = s;
        csr_w[slot] = rsqrtf((float)((deg[s] + 1) * (deg[d] + 1)));
    } else if (b < 4352) {
        int i = (b - 256) * 256 + tid;
        float4 a = ((const float4*)x)[i];
        ushort4 o;
        o.x = f2bf(a.x); o.y = f2bf(a.y); o.z = f2bf(a.z); o.w = f2bf(a.w);
        ((ushort4*)xb)[i] = o;
    } else if (b < 6400) {
        int bb = b - 4352;                       // W1: K=512, N=4096
        transpose_body(W1, W1t, F_IN, HID1, (bb >> 7) * 32, (bb & 127) * 32, tid, t);
    } else if (b < 10496) {
        int bb = b - 6400;                       // W2: K=4096, N=1024
        transpose_body(W2, W2t, HID1, HID2, (bb >> 5) * 32, (bb & 31) * 32, tid, t);
    } else {
        // W3 [1024,10] f32 -> w3b [10][W3B_STRIDE] bf16 (transposed)
        for (int i = tid; i < HID2 * F_OUT; i += 256) {
            int k = i / F_OUT, c = i % F_OUT;
            w3b[c * W3B_STRIDE + k] = f2bf(W3[i]);
        }
    }
}

// ---------------------------------------------------------------------------
// agg1: agg_x[v,:] = sum_e w_e*xb[src,:] + xb[v,:]/(deg+1) -> bf16
// 1 node per wave (64 lanes x uint4 = 1 KB row), 4 nodes/block.
// ---------------------------------------------------------------------------
__global__ __launch_bounds__(256) void agg1_kernel(
        const unsigned short* __restrict__ xb, const int* __restrict__ row_ptr,
        const int* __restrict__ csr_src, const float* __restrict__ csr_w,
        const int* __restrict__ deg, unsigned short* __restrict__ out) {
    int v = blockIdx.x * 4 + (threadIdx.x >> 6);
    int t = threadIdx.x & 63;
    const uint4* xp = (const uint4*)xb;        // row stride 64 uint4
    float sw = 1.0f / (float)(deg[v] + 1);
    float acc[8], tmp[8];
    unpack8(xp[(size_t)v * 64 + t], tmp);
#pragma unroll
    for (int j = 0; j < 8; j++) acc[j] = sw * tmp[j];
    int e = row_ptr[v], end = row_ptr[v + 1];
    for (; e + 2 <= end; e += 2) {
        int s0 = csr_src[e], s1 = csr_src[e + 1];
        float w0 = csr_w[e], w1 = csr_w[e + 1];
        float f0[8], f1[8];
        unpack8(xp[(size_t)s0 * 64 + t], f0);
        unpack8(xp[(size_t)s1 * 64 + t], f1);
#pragma unroll
        for (int j = 0; j < 8; j++) acc[j] += w0 * f0[j] + w1 * f1[j];
    }
    if (e < end) {
        int s = csr_src[e];
        float w = csr_w[e];
        float f0[8];
        unpack8(xp[(size_t)s * 64 + t], f0);
#pragma unroll
        for (int j = 0; j < 8; j++) acc[j] += w * f0[j];
    }
    ((uint4*)out)[(size_t)v * 64 + t] = pack8(acc);
}

// ---------------------------------------------------------------------------
// agg2 + gemm3 fused (unchanged)
// ---------------------------------------------------------------------------
__global__ __launch_bounds__(256) void agg2_gemm3_kernel(
        const unsigned short* __restrict__ h, const int* __restrict__ row_ptr,
        const int* __restrict__ csr_src, const float* __restrict__ csr_w,
        const int* __restrict__ deg, const float* __restrict__ b2,
        const unsigned short* __restrict__ w3b, float* __restrict__ H3) {
    __shared__ unsigned short w3s[F_OUT * W3B_STRIDE];   // ~20.2 KB
    __shared__ float red[4][F_OUT];
    int tid = threadIdx.x;
    for (int i = tid; i < F_OUT * W3B_STRIDE; i += 256) w3s[i] = w3b[i];
    __syncthreads();
    int half = tid >> 7;
    int t = tid & 127;
    int v = blockIdx.x * 2 + half;
    const uint4* hp = (const uint4*)h;   // row stride 128 uint4
    float sw = 1.0f / (float)(deg[v] + 1);
    float acc[8], tmp[8];
    unpack8(hp[(size_t)v * 128 + t], tmp);
#pragma unroll
    for (int j = 0; j < 8; j++) acc[j] = sw * tmp[j];
    int e = row_ptr[v], end = row_ptr[v + 1];
    for (; e + 2 <= end; e += 2) {
        int s0 = csr_src[e], s1 = csr_src[e + 1];
        float w0 = csr_w[e], w1 = csr_w[e + 1];
        float f0[8], f1[8];
        unpack8(hp[(size_t)s0 * 128 + t], f0);
        unpack8(hp[(size_t)s1 * 128 + t], f1);
#pragma unroll
        for (int j = 0; j < 8; j++) acc[j] += w0 * f0[j] + w1 * f1[j];
    }
    if (e < end) {
        int s = csr_src[e];
        float w = csr_w[e];
        float f0[8];
        unpack8(hp[(size_t)s * 128 + t], f0);
#pragma unroll
        for (int j = 0; j < 8; j++) acc[j] += w * f0[j];
    }
    float4 b4a = ((const float4*)b2)[t * 2];
    float4 b4b = ((const float4*)b2)[t * 2 + 1];
    acc[0] = fmaxf(acc[0] + b4a.x, 0.0f); acc[1] = fmaxf(acc[1] + b4a.y, 0.0f);
    acc[2] = fmaxf(acc[2] + b4a.z, 0.0f); acc[3] = fmaxf(acc[3] + b4a.w, 0.0f);
    acc[4] = fmaxf(acc[4] + b4b.x, 0.0f); acc[5] = fmaxf(acc[5] + b4b.y, 0.0f);
    acc[6] = fmaxf(acc[6] + b4b.z, 0.0f); acc[7] = fmaxf(acc[7] + b4b.w, 0.0f);

    float partial[F_OUT];
#pragma unroll
    for (int c = 0; c < F_OUT; c++) {
        float wf[8];
        unpack8(*(const uint4*)&w3s[c * W3B_STRIDE + t * 8], wf);
        partial[c] = acc[0] * wf[0] + acc[1] * wf[1] + acc[2] * wf[2] + acc[3] * wf[3]
                   + acc[4] * wf[4] + acc[5] * wf[5] + acc[6] * wf[6] + acc[7] * wf[7];
    }
#pragma unroll
    for (int c = 0; c < F_OUT; c++) {
#pragma unroll
        for (int off = 32; off > 0; off >>= 1)
            partial[c] += __shfl_xor(partial[c], off, 64);
    }
    int wave = tid >> 6, lane = tid & 63;
    if (lane == 0) {
#pragma unroll
        for (int c = 0; c < F_OUT; c++) red[wave][c] = partial[c];
    }
    __syncthreads();
    if (tid < 2 * F_OUT) {
        int hh = tid / F_OUT, c = tid % F_OUT;
        H3[(size_t)(blockIdx.x * 2 + hh) * H3_STRIDE + c] =
            red[hh * 2][c] + red[hh * 2 + 1][c];
    }
}

// ---------------------------------------------------------------------------
// GEMM2 (R9 experiment): 128x128 tile, BK=64, 32x32x16 MFMA, DOUBLE-BUFFERED
// LDS with buffer_load->VGPR->ds_write staging and 2-deep global prefetch.
// The barrier no longer needs vmcnt(0): tile i+2 loads (VGPR targets, no
// consumer until next iter's ds_write) stay in flight across it.
// ---------------------------------------------------------------------------
template <bool OUT_BF16, bool BIAS, bool RELU>
__global__ __launch_bounds__(256) void gemm2_dbuf_kernel(
        const unsigned short* __restrict__ A,   // [M,K] bf16
        const unsigned short* __restrict__ Bt,  // [N,K] bf16
        const float* __restrict__ bias,         // [N] or null
        void* __restrict__ C,                   // [M,N] bf16 or f32
        int M, int N, int K) {
    __shared__ unsigned short As[2][128 * 64];  // 32 KB
    __shared__ unsigned short Bs[2][128 * 64];  // 32 KB
    int tid = threadIdx.x;
    int wave = tid >> 6, lane = tid & 63;
    int wm = wave >> 1, wn = wave & 1;
    int GN = N >> 7;
    int b = blockIdx.x;
    int ntile = (b >> 3) % GN;
    int mtile = ((b >> 3) / GN) * 8 + (b & 7);
    int m0 = mtile * 128, n0 = ntile * 128;
    int lrow = lane & 31, lhalf = lane >> 5;

    // Per-thread staging addresses (XOR-swizzled source chunk, same as R8)
    const uint4* gA[4];
    const uint4* gB[4];
#pragma unroll
    for (int j = 0; j < 4; j++) {
        int idx = j * 256 + tid;
        int r = idx >> 3;
        int kc = (idx & 7) ^ (r & 7);
        gA[j] = (const uint4*)(A + (size_t)(m0 + r) * K + kc * 8);
        gB[j] = (const uint4*)(Bt + (size_t)(n0 + r) * K + kc * 8);
    }

    floatx16 acc[2][2] = {};
    uint4 ra[4], rb[4];
    int nIter = K >> 6;

    // Prologue: tile0 -> regs -> buf0; tile1 -> regs (in flight)
#pragma unroll
    for (int j = 0; j < 4; j++) { ra[j] = gA[j][0]; rb[j] = gB[j][0]; }
#pragma unroll
    for (int j = 0; j < 4; j++) {
        *(uint4*)&As[0][(j * 256 + tid) * 8] = ra[j];
        *(uint4*)&Bs[0][(j * 256 + tid) * 8] = rb[j];
    }
#pragma unroll
    for (int j = 0; j < 4; j++) { ra[j] = gA[j][8]; rb[j] = gB[j][8]; }  // +64 elems = 8 uint4
    __syncthreads();

    for (int i = 0; i < nIter; i++) {
        int cur = i & 1;
        // 1) stash tile i+1 into the other buffer (waits only on its loads)
        if (i + 1 < nIter) {
#pragma unroll
            for (int j = 0; j < 4; j++) {
                *(uint4*)&As[1 - cur][(j * 256 + tid) * 8] = ra[j];
                *(uint4*)&Bs[1 - cur][(j * 256 + tid) * 8] = rb[j];
            }
        }
        // 2) issue loads for tile i+2 (cross the barrier in flight)
        if (i + 2 < nIter) {
#pragma unroll
            for (int j = 0; j < 4; j++) {
                ra[j] = gA[j][(i + 2) * 8];
                rb[j] = gB[j][(i + 2) * 8];
            }
        }
        // 3) MFMA from current buffer
#pragma unroll
        for (int kk = 0; kk < 4; kk++) {
            bf16x8 af[2], bfr[2];
            int c = kk * 2 + lhalf;
#pragma unroll
            for (int mt = 0; mt < 2; mt++) {
                int R = wm * 64 + mt * 32 + lrow;
                af[mt] = *(const bf16x8*)&As[cur][(R * 8 + (c ^ (R & 7))) * 8];
            }
#pragma unroll
            for (int nt = 0; nt < 2; nt++) {
                int R = wn * 64 + nt * 32 + lrow;
                bfr[nt] = *(const bf16x8*)&Bs[cur][(R * 8 + (c ^ (R & 7))) * 8];
            }
#pragma unroll
            for (int mt = 0; mt < 2; mt++)
#pragma unroll
                for (int nt = 0; nt < 2; nt++)
                    acc[mt][nt] = __builtin_amdgcn_mfma_f32_32x32x16_bf16(
                        af[mt], bfr[nt], acc[mt][nt], 0, 0, 0);
        }
        // 4) one barrier per iter
        __syncthreads();
    }

#pragma unroll
    for (int mt = 0; mt < 2; mt++) {
#pragma unroll
        for (int nt = 0; nt < 2; nt++) {
            int col = n0 + wn * 64 + nt * 32 + lrow;
            float bv = BIAS ? bias[col] : 0.0f;
#pragma unroll
            for (int reg = 0; reg < 16; reg++) {
                int row = m0 + wm * 64 + mt * 32 + (reg & 3) + 8 * (reg >> 2) + 4 * lhalf;
                float v = acc[mt][nt][reg] + bv;
                if (RELU) v = fmaxf(v, 0.0f);
                if (OUT_BF16)
                    ((unsigned short*)C)[(size_t)row * N + col] = f2bf(v);
                else
                    ((float*)C)[(size_t)row * N + col] = v;
            }
        }
    }
}

// ---------------------------------------------------------------------------
// GEMM1: 256x128 tile, BK=64, 32x32x16 MFMA (unchanged control).
// ---------------------------------------------------------------------------
__global__ __launch_bounds__(256, 2) void gemm1_mfma_kernel(
        const unsigned short* __restrict__ A,   // [8192,512] bf16
        const unsigned short* __restrict__ Bt,  // [4096,512] bf16
        const float* __restrict__ bias,         // [4096]
        unsigned short* __restrict__ C) {       // [8192,4096] bf16
    __shared__ unsigned short As[256 * 64];     // 32 KB
    __shared__ unsigned short Bs[128 * 64];     // 16 KB
    const int K = F_IN, N = HID1;
    int tid = threadIdx.x;
    int wave = tid >> 6, lane = tid & 63;
    int wm = wave >> 1, wn = wave & 1;          // 2x2 waves, wave-tile 128x64
    int b = blockIdx.x;
    int GN = N >> 7;                            // 32 n-tiles
    int ntile = (b >> 3) % GN;
    int mtile = ((b >> 3) / GN) * 8 + (b & 7);  // 0..31
    int m0 = mtile * 256, n0 = ntile * 128;
    int lrow = lane & 31, lhalf = lane >> 5;

    floatx16 acc[4][2] = {};

    for (int k0 = 0; k0 < K; k0 += 64) {
#pragma unroll
        for (int j = 0; j < 8; j++) {           // A: 2048 slots
            int idx = j * 256 + tid;
            int r = idx >> 3;                   // 0..255
            int kc = (idx & 7) ^ (r & 7);
            __builtin_amdgcn_global_load_lds(
                (const __attribute__((address_space(1))) void*)(A + (size_t)(m0 + r) * K + k0 + kc * 8),
                (__attribute__((address_space(3))) void*)(&As[idx * 8]), 16, 0, 0);
        }
#pragma unroll
        for (int j = 0; j < 4; j++) {           // B: 1024 slots
            int idx = j * 256 + tid;
            int r = idx >> 3;                   // 0..127
            int kc = (idx & 7) ^ (r & 7);
            __builtin_amdgcn_global_load_lds(
                (const __attribute__((address_space(1))) void*)(Bt + (size_t)(n0 + r) * K + k0 + kc * 8),
                (__attribute__((address_space(3))) void*)(&Bs[idx * 8]), 16, 0, 0);
        }
        __syncthreads();
#pragma unroll
        for (int kk = 0; kk < 4; kk++) {
            bf16x8 af[4], bfr[2];
            int c = kk * 2 + lhalf;
#pragma unroll
            for (int mt = 0; mt < 4; mt++) {
                int R = wm * 128 + mt * 32 + lrow;
                af[mt] = *(const bf16x8*)&As[(R * 8 + (c ^ (R & 7))) * 8];
            }
#pragma unroll
            for (int nt = 0; nt < 2; nt++) {
                int R = wn * 64 + nt * 32 + lrow;
                bfr[nt] = *(const bf16x8*)&Bs[(R * 8 + (c ^ (R & 7))) * 8];
            }
#pragma unroll
            for (int mt = 0; mt < 4; mt++)
#pragma unroll
                for (int nt = 0; nt < 2; nt++)
                    acc[mt][nt] = __builtin_amdgcn_mfma_f32_32x32x16_bf16(
                        af[mt], bfr[nt], acc[mt][nt], 0, 0, 0);
        }
        __syncthreads();
    }

#pragma unroll
    for (int mt = 0; mt < 4; mt++) {
#pragma unroll
        for (int nt = 0; nt < 2; nt++) {
            int col = n0 + wn * 64 + nt * 32 + lrow;
            float bv = bias[col];
#pragma unroll
            for (int reg = 0; reg < 16; reg++) {
                int row = m0 + wm * 128 + mt * 32 + (reg & 3) + 8 * (reg >> 2) + 4 * lhalf;
                float v = fmaxf(acc[mt][nt][reg] + bv, 0.0f);
                C[(size_t)row * N + col] = f2bf(v);
            }
        }
    }
}

// ---------------------------------------------------------------------------
// Final: aggregate h3 (stride 16), add b3, log_softmax per node.
// ---------------------------------------------------------------------------
__global__ void final_kernel(const float* __restrict__ h3, const int* __restrict__ row_ptr,
                             const int* __restrict__ csr_src, const float* __restrict__ csr_w,
                             const int* __restrict__ deg, const float* __restrict__ b3,
                             float* __restrict__ out) {
    int v = blockIdx.x * blockDim.x + threadIdx.x;
    if (v >= N_NODES) return;
    const float4* h4 = (const float4*)h3;
    float sw = 1.0f / (float)(deg[v] + 1);
    float a[12];
    *(float4*)&a[0] = h4[v * 4];
    *(float4*)&a[4] = h4[v * 4 + 1];
    *(float4*)&a[8] = h4[v * 4 + 2];
    float acc[F_OUT];
#pragma unroll
    for (int c = 0; c < F_OUT; c++) acc[c] = b3[c] + sw * a[c];
    int end = row_ptr[v + 1];
    for (int e = row_ptr[v]; e < end; e++) {
        int s = csr_src[e];
        float w = csr_w[e];
        float bsrc[12];
        *(float4*)&bsrc[0] = h4[s * 4];
        *(float4*)&bsrc[4] = h4[s * 4 + 1];
        *(float4*)&bsrc[8] = h4[s * 4 + 2];
#pragma unroll
        for (int c = 0; c < F_OUT; c++) acc[c] += w * bsrc[c];
    }
    float m = acc[0];
#pragma unroll
    for (int c = 1; c < F_OUT; c++) m = fmaxf(m, acc[c]);
    float ssum = 0.0f;
#pragma unroll
    for (int c = 0; c < F_OUT; c++) ssum += expf(acc[c] - m);
    float l = logf(ssum);
#pragma unroll
    for (int c = 0; c < F_OUT; c++) out[v * F_OUT + c] = acc[c] - m - l;
}

// ---------------------------------------------------------------------------
// Launch (7 dispatches)
// ---------------------------------------------------------------------------
extern "C" void kernel_launch(void* const* d_in, const int* in_sizes, int n_in,
                              void* d_out, int out_size, void* d_ws, size_t ws_size,
                              hipStream_t stream) {
    const float* x  = (const float*)d_in[0];
    const float* W1 = (const float*)d_in[1];
    const float* b1 = (const float*)d_in[2];
    const float* W2 = (const float*)d_in[3];
    const float* b2 = (const float*)d_in[4];
    const float* W3 = (const float*)d_in[5];
    const float* b3 = (const float*)d_in[6];
    const int*   ei = (const int*)d_in[7];
    float* out = (float*)d_out;

    char* p = (char*)d_ws;
    int*   deg     = (int*)p;    p += N_NODES * 4;
    int*   cnt     = (int*)p;    p += N_NODES * 4;
    int*   row_ptr = (int*)p;    p += 33024;
    int*   csr_src = (int*)p;    p += N_EDGES * 4;
    float* csr_w   = (float*)p;  p += N_EDGES * 4;
    float* h3      = (float*)p;  p += N_NODES * H3_STRIDE * 4;
    unsigned short* w3b = (unsigned short*)p; p += (F_OUT * W3B_STRIDE * 2 + 255) / 256 * 256;
    unsigned short* xb    = (unsigned short*)p; p += (size_t)N_NODES * F_IN * 2;
    unsigned short* agg_x = (unsigned short*)p; p += (size_t)N_NODES * F_IN * 2;
    unsigned short* W1t   = (unsigned short*)p; p += (size_t)HID1 * F_IN * 2;
    unsigned short* W2t   = (unsigned short*)p; p += (size_t)HID2 * HID1 * 2;
    unsigned short* h1    = (unsigned short*)p; p += (size_t)N_NODES * HID1 * 2;
    unsigned short* h2pre = (unsigned short*)p; p += (size_t)N_NODES * HID2 * 2;

    // Graph preprocessing + all conversions (2 launches)
    hist_scan_kernel<<<1, 1024, 0, stream>>>(ei, deg, row_ptr, cnt);
    megaprep_kernel<<<10497, 256, 0, stream>>>(ei, deg, row_ptr, cnt, csr_src, csr_w,
                                               x, xb, W1, W1t, W2, W2t, W3, w3b);

    // Layer 1
    agg1_kernel<<<N_NODES / 4, 256, 0, stream>>>(xb, row_ptr, csr_src, csr_w, deg, agg_x);
    gemm1_mfma_kernel<<<(HID1 / 128) * (N_NODES / 256), 256, 0, stream>>>(agg_x, W1t, b1, h1);

    // Layer 2 (double-buffered experiment)
    gemm2_dbuf_kernel<true, false, false><<<(HID2 / 128) * (N_NODES / 128), 256, 0, stream>>>(
        h1, W2t, nullptr, h2pre, N_NODES, HID2, HID1);

    // Layer 2 aggregation + Layer 3 GEMM fused
    agg2_gemm3_kernel<<<N_NODES / 2, 256, 0, stream>>>(h2pre, row_ptr, csr_src, csr_w,
                                                       deg, b2, w3b, h3);

    // Output
    final_kernel<<<N_NODES / 256, 256, 0, stream>>>(h3, row_ptr, csr_src, csr_w, deg, b3, out);
}

// Round 10
// 307.690 us; speedup vs baseline: 1.2592x; 1.2592x over previous
//
#include <hip/hip_runtime.h>
#include <math.h>

#define N_NODES 8192
#define N_EDGES 65536
#define F_IN    512
#define HID1    4096
#define HID2    1024
#define F_OUT   10
#define H3_STRIDE 16
#define W3B_STRIDE 1032   // padded K-stride of bf16 W3^T rows

typedef __bf16 bf16x8 __attribute__((ext_vector_type(8)));
typedef float floatx4 __attribute__((ext_vector_type(4)));
typedef float floatx16 __attribute__((ext_vector_type(16)));

static __device__ __forceinline__ unsigned short f2bf(float f) {
    union { float f; unsigned u; } v; v.f = f;
    unsigned r = v.u + 0x7fffu + ((v.u >> 16) & 1u);   // RNE
    return (unsigned short)(r >> 16);
}
static __device__ __forceinline__ float bf2f(unsigned short u) {
    union { unsigned u; float f; } v; v.u = ((unsigned)u) << 16;
    return v.f;
}
static __device__ __forceinline__ void unpack8(uint4 r, float* f) {
    union { unsigned u; float v; } c;
    c.u = r.x << 16;          f[0] = c.v;
    c.u = r.x & 0xffff0000u;  f[1] = c.v;
    c.u = r.y << 16;          f[2] = c.v;
    c.u = r.y & 0xffff0000u;  f[3] = c.v;
    c.u = r.z << 16;          f[4] = c.v;
    c.u = r.z & 0xffff0000u;  f[5] = c.v;
    c.u = r.w << 16;          f[6] = c.v;
    c.u = r.w & 0xffff0000u;  f[7] = c.v;
}
static __device__ __forceinline__ uint4 pack8(const float* f) {
    uint4 o;
    o.x = (unsigned)f2bf(f[0]) | ((unsigned)f2bf(f[1]) << 16);
    o.y = (unsigned)f2bf(f[2]) | ((unsigned)f2bf(f[3]) << 16);
    o.z = (unsigned)f2bf(f[4]) | ((unsigned)f2bf(f[5]) << 16);
    o.w = (unsigned)f2bf(f[6]) | ((unsigned)f2bf(f[7]) << 16);
    return o;
}

// ---------------------------------------------------------------------------
// hist+scan (one block): deg[] via LDS histogram, exclusive scan -> row_ptr,
// cnt[] zeroing.
// ---------------------------------------------------------------------------
__global__ __launch_bounds__(1024) void hist_scan_kernel(
        const int* __restrict__ ei, int* __restrict__ deg,
        int* __restrict__ row_ptr, int* __restrict__ cnt) {
    __shared__ int hist[N_NODES];        // 32 KB
    __shared__ int sums[1024];
    int t = threadIdx.x;
#pragma unroll
    for (int i = 0; i < 8; i++) hist[t + i * 1024] = 0;
    __syncthreads();
#pragma unroll
    for (int i = 0; i < 64; i++) {
        int d = ei[N_EDGES + i * 1024 + t];
        atomicAdd(&hist[d], 1);
    }
    __syncthreads();
    int base = t * 8;
    int local[8], run = 0;
#pragma unroll
    for (int i = 0; i < 8; i++) {
        int dv = hist[base + i];
        deg[base + i] = dv;
        cnt[base + i] = 0;
        local[i] = run; run += dv;
    }
    sums[t] = run;
    __syncthreads();
    for (int off = 1; off < 1024; off <<= 1) {
        int val = (t >= off) ? sums[t - off] : 0;
        __syncthreads();
        sums[t] += val;
        __syncthreads();
    }
    int offset = (t == 0) ? 0 : sums[t - 1];
#pragma unroll
    for (int i = 0; i < 8; i++) row_ptr[base + i] = offset + local[i];
    if (t == 1023) row_ptr[N_NODES] = sums[1023];
}

// ---------------------------------------------------------------------------
// megaprep: fill CSR (blocks 0..255) + xcvt (256..4351) + W1^T (4352..6399)
// + W2^T (6400..10495) + W3 bf16 cvt (10496). One launch.
// ---------------------------------------------------------------------------
static __device__ __forceinline__ void transpose_body(
        const float* __restrict__ W, unsigned short* __restrict__ Wt,
        int K, int N, int k0, int n0, int tid, float (*t)[33]) {
    int c = tid & 31, r8 = tid >> 5;
#pragma unroll
    for (int i = 0; i < 4; i++) {
        int r = r8 + i * 8;
        t[r][c] = W[(size_t)(k0 + r) * N + n0 + c];
    }
    __syncthreads();
#pragma unroll
    for (int i = 0; i < 4; i++) {
        int r = r8 + i * 8;
        Wt[(size_t)(n0 + r) * K + k0 + c] = f2bf(t[c][r]);
    }
}

__global__ __launch_bounds__(256) void megaprep_kernel(
        const int* __restrict__ ei, const int* __restrict__ deg,
        const int* __restrict__ row_ptr, int* __restrict__ cnt,
        int* __restrict__ csr_src, float* __restrict__ csr_w,
        const float* __restrict__ x, unsigned short* __restrict__ xb,
        const float* __restrict__ W1, unsigned short* __restrict__ W1t,
        const float* __restrict__ W2, unsigned short* __restrict__ W2t,
        const float* __restrict__ W3, unsigned short* __restrict__ w3b) {
    __shared__ float t[32][33];
    int b = blockIdx.x, tid = threadIdx.x;
    if (b < 256) {
        int e = b * 256 + tid;
        int s = ei[e];
        int d = ei[N_EDGES + e];
        int slot = row_ptr[d] + atomicAdd(&cnt[d], 1);
        csr_src[slot] = s;
        csr_w[slot] = rsqrtf((float)((deg[s] + 1) * (deg[d] + 1)));
    } else if (b < 4352) {
        int i = (b - 256) * 256 + tid;
        float4 a = ((const float4*)x)[i];
        ushort4 o;
        o.x = f2bf(a.x); o.y = f2bf(a.y); o.z = f2bf(a.z); o.w = f2bf(a.w);
        ((ushort4*)xb)[i] = o;
    } else if (b < 6400) {
        int bb = b - 4352;                       // W1: K=512, N=4096
        transpose_body(W1, W1t, F_IN, HID1, (bb >> 7) * 32, (bb & 127) * 32, tid, t);
    } else if (b < 10496) {
        int bb = b - 6400;                       // W2: K=4096, N=1024
        transpose_body(W2, W2t, HID1, HID2, (bb >> 5) * 32, (bb & 31) * 32, tid, t);
    } else {
        // W3 [1024,10] f32 -> w3b [10][W3B_STRIDE] bf16 (transposed)
        for (int i = tid; i < HID2 * F_OUT; i += 256) {
            int k = i / F_OUT, c = i % F_OUT;
            w3b[c * W3B_STRIDE + k] = f2bf(W3[i]);
        }
    }
}

// ---------------------------------------------------------------------------
// agg1: agg_x[v,:] = sum_e w_e*xb[src,:] + xb[v,:]/(deg+1) -> bf16
// 1 node per wave (64 lanes x uint4 = 1 KB row), 4 nodes/block.
// ---------------------------------------------------------------------------
__global__ __launch_bounds__(256) void agg1_kernel(
        const unsigned short* __restrict__ xb, const int* __restrict__ row_ptr,
        const int* __restrict__ csr_src, const float* __restrict__ csr_w,
        const int* __restrict__ deg, unsigned short* __restrict__ out) {
    int v = blockIdx.x * 4 + (threadIdx.x >> 6);
    int t = threadIdx.x & 63;
    const uint4* xp = (const uint4*)xb;        // row stride 64 uint4
    float sw = 1.0f / (float)(deg[v] + 1);
    float acc[8], tmp[8];
    unpack8(xp[(size_t)v * 64 + t], tmp);
#pragma unroll
    for (int j = 0; j < 8; j++) acc[j] = sw * tmp[j];
    int e = row_ptr[v], end = row_ptr[v + 1];
    for (; e + 2 <= end; e += 2) {
        int s0 = csr_src[e], s1 = csr_src[e + 1];
        float w0 = csr_w[e], w1 = csr_w[e + 1];
        float f0[8], f1[8];
        unpack8(xp[(size_t)s0 * 64 + t], f0);
        unpack8(xp[(size_t)s1 * 64 + t], f1);
#pragma unroll
        for (int j = 0; j < 8; j++) acc[j] += w0 * f0[j] + w1 * f1[j];
    }
    if (e < end) {
        int s = csr_src[e];
        float w = csr_w[e];
        float f0[8];
        unpack8(xp[(size_t)s * 64 + t], f0);
#pragma unroll
        for (int j = 0; j < 8; j++) acc[j] += w * f0[j];
    }
    ((uint4*)out)[(size_t)v * 64 + t] = pack8(acc);
}

// ---------------------------------------------------------------------------
// agg2 + gemm3 fused (unchanged)
// ---------------------------------------------------------------------------
__global__ __launch_bounds__(256) void agg2_gemm3_kernel(
        const unsigned short* __restrict__ h, const int* __restrict__ row_ptr,
        const int* __restrict__ csr_src, const float* __restrict__ csr_w,
        const int* __restrict__ deg, const float* __restrict__ b2,
        const unsigned short* __restrict__ w3b, float* __restrict__ H3) {
    __shared__ unsigned short w3s[F_OUT * W3B_STRIDE];   // ~20.2 KB
    __shared__ float red[4][F_OUT];
    int tid = threadIdx.x;
    for (int i = tid; i < F_OUT * W3B_STRIDE; i += 256) w3s[i] = w3b[i];
    __syncthreads();
    int half = tid >> 7;
    int t = tid & 127;
    int v = blockIdx.x * 2 + half;
    const uint4* hp = (const uint4*)h;   // row stride 128 uint4
    float sw = 1.0f / (float)(deg[v] + 1);
    float acc[8], tmp[8];
    unpack8(hp[(size_t)v * 128 + t], tmp);
#pragma unroll
    for (int j = 0; j < 8; j++) acc[j] = sw * tmp[j];
    int e = row_ptr[v], end = row_ptr[v + 1];
    for (; e + 2 <= end; e += 2) {
        int s0 = csr_src[e], s1 = csr_src[e + 1];
        float w0 = csr_w[e], w1 = csr_w[e + 1];
        float f0[8], f1[8];
        unpack8(hp[(size_t)s0 * 128 + t], f0);
        unpack8(hp[(size_t)s1 * 128 + t], f1);
#pragma unroll
        for (int j = 0; j < 8; j++) acc[j] += w0 * f0[j] + w1 * f1[j];
    }
    if (e < end) {
        int s = csr_src[e];
        float w = csr_w[e];
        float f0[8];
        unpack8(hp[(size_t)s * 128 + t], f0);
#pragma unroll
        for (int j = 0; j < 8; j++) acc[j] += w * f0[j];
    }
    float4 b4a = ((const float4*)b2)[t * 2];
    float4 b4b = ((const float4*)b2)[t * 2 + 1];
    acc[0] = fmaxf(acc[0] + b4a.x, 0.0f); acc[1] = fmaxf(acc[1] + b4a.y, 0.0f);
    acc[2] = fmaxf(acc[2] + b4a.z, 0.0f); acc[3] = fmaxf(acc[3] + b4a.w, 0.0f);
    acc[4] = fmaxf(acc[4] + b4b.x, 0.0f); acc[5] = fmaxf(acc[5] + b4b.y, 0.0f);
    acc[6] = fmaxf(acc[6] + b4b.z, 0.0f); acc[7] = fmaxf(acc[7] + b4b.w, 0.0f);

    float partial[F_OUT];
#pragma unroll
    for (int c = 0; c < F_OUT; c++) {
        float wf[8];
        unpack8(*(const uint4*)&w3s[c * W3B_STRIDE + t * 8], wf);
        partial[c] = acc[0] * wf[0] + acc[1] * wf[1] + acc[2] * wf[2] + acc[3] * wf[3]
                   + acc[4] * wf[4] + acc[5] * wf[5] + acc[6] * wf[6] + acc[7] * wf[7];
    }
#pragma unroll
    for (int c = 0; c < F_OUT; c++) {
#pragma unroll
        for (int off = 32; off > 0; off >>= 1)
            partial[c] += __shfl_xor(partial[c], off, 64);
    }
    int wave = tid >> 6, lane = tid & 63;
    if (lane == 0) {
#pragma unroll
        for (int c = 0; c < F_OUT; c++) red[wave][c] = partial[c];
    }
    __syncthreads();
    if (tid < 2 * F_OUT) {
        int hh = tid / F_OUT, c = tid % F_OUT;
        H3[(size_t)(blockIdx.x * 2 + hh) * H3_STRIDE + c] =
            red[hh * 2][c] + red[hh * 2 + 1][c];
    }
}

// ---------------------------------------------------------------------------
// GEMM2 (R10): 64x128 tile, BK=64, 32x32x16 MFMA, global_load_lds staging.
// Smaller tile -> 1024 blocks -> 4 blocks/CU (was 2): gemm2 was latency-
// bound at 20% occupancy; double the waves/CU to hide barrier drain.
// Wave-tile 32x64 = 1x2 frags; LDS 24 KB; __launch_bounds__(256,4).
// ---------------------------------------------------------------------------
template <bool OUT_BF16, bool BIAS, bool RELU>
__global__ __launch_bounds__(256, 4) void gemm2_mfma_kernel(
        const unsigned short* __restrict__ A,   // [M,K] bf16
        const unsigned short* __restrict__ Bt,  // [N,K] bf16
        const float* __restrict__ bias,         // [N] or null
        void* __restrict__ C,                   // [M,N] bf16 or f32
        int M, int N, int K) {
    __shared__ unsigned short As[64 * 64];      // 8 KB
    __shared__ unsigned short Bs[128 * 64];     // 16 KB
    int tid = threadIdx.x;
    int wave = tid >> 6, lane = tid & 63;
    int wm = wave >> 1, wn = wave & 1;          // 2x2 waves, wave-tile 32x64
    int GN = N >> 7;                            // 8 n-tiles
    int b = blockIdx.x;
    int ntile = (b >> 3) % GN;
    int mtile = ((b >> 3) / GN) * 8 + (b & 7);  // 0..127
    int m0 = mtile * 64, n0 = ntile * 128;
    int lrow = lane & 31, lhalf = lane >> 5;

    floatx16 acc[2] = {};

    for (int k0 = 0; k0 < K; k0 += 64) {
#pragma unroll
        for (int j = 0; j < 2; j++) {           // A: 512 slots
            int idx = j * 256 + tid;
            int r = idx >> 3;                   // 0..63
            int kc = (idx & 7) ^ (r & 7);
            __builtin_amdgcn_global_load_lds(
                (const __attribute__((address_space(1))) void*)(A + (size_t)(m0 + r) * K + k0 + kc * 8),
                (__attribute__((address_space(3))) void*)(&As[idx * 8]), 16, 0, 0);
        }
#pragma unroll
        for (int j = 0; j < 4; j++) {           // B: 1024 slots
            int idx = j * 256 + tid;
            int r = idx >> 3;                   // 0..127
            int kc = (idx & 7) ^ (r & 7);
            __builtin_amdgcn_global_load_lds(
                (const __attribute__((address_space(1))) void*)(Bt + (size_t)(n0 + r) * K + k0 + kc * 8),
                (__attribute__((address_space(3))) void*)(&Bs[idx * 8]), 16, 0, 0);
        }
        __syncthreads();
#pragma unroll
        for (int kk = 0; kk < 4; kk++) {
            bf16x8 af, bfr[2];
            int c = kk * 2 + lhalf;
            {
                int R = wm * 32 + lrow;
                af = *(const bf16x8*)&As[(R * 8 + (c ^ (R & 7))) * 8];
            }
#pragma unroll
            for (int nt = 0; nt < 2; nt++) {
                int R = wn * 64 + nt * 32 + lrow;
                bfr[nt] = *(const bf16x8*)&Bs[(R * 8 + (c ^ (R & 7))) * 8];
            }
#pragma unroll
            for (int nt = 0; nt < 2; nt++)
                acc[nt] = __builtin_amdgcn_mfma_f32_32x32x16_bf16(
                    af, bfr[nt], acc[nt], 0, 0, 0);
        }
        __syncthreads();
    }

#pragma unroll
    for (int nt = 0; nt < 2; nt++) {
        int col = n0 + wn * 64 + nt * 32 + lrow;
        float bv = BIAS ? bias[col] : 0.0f;
#pragma unroll
        for (int reg = 0; reg < 16; reg++) {
            int row = m0 + wm * 32 + (reg & 3) + 8 * (reg >> 2) + 4 * lhalf;
            float v = acc[nt][reg] + bv;
            if (RELU) v = fmaxf(v, 0.0f);
            if (OUT_BF16)
                ((unsigned short*)C)[(size_t)row * N + col] = f2bf(v);
            else
                ((float*)C)[(size_t)row * N + col] = v;
        }
    }
}

// ---------------------------------------------------------------------------
// GEMM1: 256x128 tile, BK=64, 32x32x16 MFMA (unchanged control).
// ---------------------------------------------------------------------------
__global__ __launch_bounds__(256, 2) void gemm1_mfma_kernel(
        const unsigned short* __restrict__ A,   // [8192,512] bf16
        const unsigned short* __restrict__ Bt,  // [4096,512] bf16
        const float* __restrict__ bias,         // [4096]
        unsigned short* __restrict__ C) {       // [8192,4096] bf16
    __shared__ unsigned short As[256 * 64];     // 32 KB
    __shared__ unsigned short Bs[128 * 64];     // 16 KB
    const int K = F_IN, N = HID1;
    int tid = threadIdx.x;
    int wave = tid >> 6, lane = tid & 63;
    int wm = wave >> 1, wn = wave & 1;          // 2x2 waves, wave-tile 128x64
    int b = blockIdx.x;
    int GN = N >> 7;                            // 32 n-tiles
    int ntile = (b >> 3) % GN;
    int mtile = ((b >> 3) / GN) * 8 + (b & 7);  // 0..31
    int m0 = mtile * 256, n0 = ntile * 128;
    int lrow = lane & 31, lhalf = lane >> 5;

    floatx16 acc[4][2] = {};

    for (int k0 = 0; k0 < K; k0 += 64) {
#pragma unroll
        for (int j = 0; j < 8; j++) {           // A: 2048 slots
            int idx = j * 256 + tid;
            int r = idx >> 3;                   // 0..255
            int kc = (idx & 7) ^ (r & 7);
            __builtin_amdgcn_global_load_lds(
                (const __attribute__((address_space(1))) void*)(A + (size_t)(m0 + r) * K + k0 + kc * 8),
                (__attribute__((address_space(3))) void*)(&As[idx * 8]), 16, 0, 0);
        }
#pragma unroll
        for (int j = 0; j < 4; j++) {           // B: 1024 slots
            int idx = j * 256 + tid;
            int r = idx >> 3;                   // 0..127
            int kc = (idx & 7) ^ (r & 7);
            __builtin_amdgcn_global_load_lds(
                (const __attribute__((address_space(1))) void*)(Bt + (size_t)(n0 + r) * K + k0 + kc * 8),
                (__attribute__((address_space(3))) void*)(&Bs[idx * 8]), 16, 0, 0);
        }
        __syncthreads();
#pragma unroll
        for (int kk = 0; kk < 4; kk++) {
            bf16x8 af[4], bfr[2];
            int c = kk * 2 + lhalf;
#pragma unroll
            for (int mt = 0; mt < 4; mt++) {
                int R = wm * 128 + mt * 32 + lrow;
                af[mt] = *(const bf16x8*)&As[(R * 8 + (c ^ (R & 7))) * 8];
            }
#pragma unroll
            for (int nt = 0; nt < 2; nt++) {
                int R = wn * 64 + nt * 32 + lrow;
                bfr[nt] = *(const bf16x8*)&Bs[(R * 8 + (c ^ (R & 7))) * 8];
            }
#pragma unroll
            for (int mt = 0; mt < 4; mt++)
#pragma unroll
                for (int nt = 0; nt < 2; nt++)
                    acc[mt][nt] = __builtin_amdgcn_mfma_f32_32x32x16_bf16(
                        af[mt], bfr[nt], acc[mt][nt], 0, 0, 0);
        }
        __syncthreads();
    }

#pragma unroll
    for (int mt = 0; mt < 4; mt++) {
#pragma unroll
        for (int nt = 0; nt < 2; nt++) {
            int col = n0 + wn * 64 + nt * 32 + lrow;
            float bv = bias[col];
#pragma unroll
            for (int reg = 0; reg < 16; reg++) {
                int row = m0 + wm * 128 + mt * 32 + (reg & 3) + 8 * (reg >> 2) + 4 * lhalf;
                float v = fmaxf(acc[mt][nt][reg] + bv, 0.0f);
                C[(size_t)row * N + col] = f2bf(v);
            }
        }
    }
}

// ---------------------------------------------------------------------------
// Final: aggregate h3 (stride 16), add b3, log_softmax per node.
// ---------------------------------------------------------------------------
__global__ void final_kernel(const float* __restrict__ h3, const int* __restrict__ row_ptr,
                             const int* __restrict__ csr_src, const float* __restrict__ csr_w,
                             const int* __restrict__ deg, const float* __restrict__ b3,
                             float* __restrict__ out) {
    int v = blockIdx.x * blockDim.x + threadIdx.x;
    if (v >= N_NODES) return;
    const float4* h4 = (const float4*)h3;
    float sw = 1.0f / (float)(deg[v] + 1);
    float a[12];
    *(float4*)&a[0] = h4[v * 4];
    *(float4*)&a[4] = h4[v * 4 + 1];
    *(float4*)&a[8] = h4[v * 4 + 2];
    float acc[F_OUT];
#pragma unroll
    for (int c = 0; c < F_OUT; c++) acc[c] = b3[c] + sw * a[c];
    int end = row_ptr[v + 1];
    for (int e = row_ptr[v]; e < end; e++) {
        int s = csr_src[e];
        float w = csr_w[e];
        float bsrc[12];
        *(float4*)&bsrc[0] = h4[s * 4];
        *(float4*)&bsrc[4] = h4[s * 4 + 1];
        *(float4*)&bsrc[8] = h4[s * 4 + 2];
#pragma unroll
        for (int c = 0; c < F_OUT; c++) acc[c] += w * bsrc[c];
    }
    float m = acc[0];
#pragma unroll
    for (int c = 1; c < F_OUT; c++) m = fmaxf(m, acc[c]);
    float ssum = 0.0f;
#pragma unroll
    for (int c = 0; c < F_OUT; c++) ssum += expf(acc[c] - m);
    float l = logf(ssum);
#pragma unroll
    for (int c = 0; c < F_OUT; c++) out[v * F_OUT + c] = acc[c] - m - l;
}

// ---------------------------------------------------------------------------
// Launch (7 dispatches)
// ---------------------------------------------------------------------------
extern "C" void kernel_launch(void* const* d_in, const int* in_sizes, int n_in,
                              void* d_out, int out_size, void* d_ws, size_t ws_size,
                              hipStream_t stream) {
    const float* x  = (const float*)d_in[0];
    const float* W1 = (const float*)d_in[1];
    const float* b1 = (const float*)d_in[2];
    const float* W2 = (const float*)d_in[3];
    const float* b2 = (const float*)d_in[4];
    const float* W3 = (const float*)d_in[5];
    const float* b3 = (const float*)d_in[6];
    const int*   ei = (const int*)d_in[7];
    float* out = (float*)d_out;

    char* p = (char*)d_ws;
    int*   deg     = (int*)p;    p += N_NODES * 4;
    int*   cnt     = (int*)p;    p += N_NODES * 4;
    int*   row_ptr = (int*)p;    p += 33024;
    int*   csr_src = (int*)p;    p += N_EDGES * 4;
    float* csr_w   = (float*)p;  p += N_EDGES * 4;
    float* h3      = (float*)p;  p += N_NODES * H3_STRIDE * 4;
    unsigned short* w3b = (unsigned short*)p; p += (F_OUT * W3B_STRIDE * 2 + 255) / 256 * 256;
    unsigned short* xb    = (unsigned short*)p; p += (size_t)N_NODES * F_IN * 2;
    unsigned short* agg_x = (unsigned short*)p; p += (size_t)N_NODES * F_IN * 2;
    unsigned short* W1t   = (unsigned short*)p; p += (size_t)HID1 * F_IN * 2;
    unsigned short* W2t   = (unsigned short*)p; p += (size_t)HID2 * HID1 * 2;
    unsigned short* h1    = (unsigned short*)p; p += (size_t)N_NODES * HID1 * 2;
    unsigned short* h2pre = (unsigned short*)p; p += (size_t)N_NODES * HID2 * 2;

    // Graph preprocessing + all conversions (2 launches)
    hist_scan_kernel<<<1, 1024, 0, stream>>>(ei, deg, row_ptr, cnt);
    megaprep_kernel<<<10497, 256, 0, stream>>>(ei, deg, row_ptr, cnt, csr_src, csr_w,
                                               x, xb, W1, W1t, W2, W2t, W3, w3b);

    // Layer 1
    agg1_kernel<<<N_NODES / 4, 256, 0, stream>>>(xb, row_ptr, csr_src, csr_w, deg, agg_x);
    gemm1_mfma_kernel<<<(HID1 / 128) * (N_NODES / 256), 256, 0, stream>>>(agg_x, W1t, b1, h1);

    // Layer 2 (64x128 tiles: 1024 blocks -> 4 blocks/CU for latency hiding)
    gemm2_mfma_kernel<true, false, false><<<(HID2 / 128) * (N_NODES / 64), 256, 0, stream>>>(
        h1, W2t, nullptr, h2pre, N_NODES, HID2, HID1);

    // Layer 2 aggregation + Layer 3 GEMM fused
    agg2_gemm3_kernel<<<N_NODES / 2, 256, 0, stream>>>(h2pre, row_ptr, csr_src, csr_w,
                                                       deg, b2, w3b, h3);

    // Output
    final_kernel<<<N_NODES / 256, 256, 0, stream>>>(h3, row_ptr, csr_src, csr_w, deg, b3, out);
}

// Round 11
// 282.682 us; speedup vs baseline: 1.3706x; 1.0885x over previous
//
#include <hip/hip_runtime.h>
#include <math.h>

#define N_NODES 8192
#define N_EDGES 65536
#define F_IN    512
#define HID1    4096
#define HID2    1024
#define F_OUT   10
#define H3_STRIDE 16
#define W3B_STRIDE 1032   // padded K-stride of bf16 W3^T rows

typedef __bf16 bf16x8 __attribute__((ext_vector_type(8)));
typedef float floatx4 __attribute__((ext_vector_type(4)));
typedef float floatx16 __attribute__((ext_vector_type(16)));

static __device__ __forceinline__ unsigned short f2bf(float f) {
    union { float f; unsigned u; } v; v.f = f;
    unsigned r = v.u + 0x7fffu + ((v.u >> 16) & 1u);   // RNE
    return (unsigned short)(r >> 16);
}
static __device__ __forceinline__ float bf2f(unsigned short u) {
    union { unsigned u; float f; } v; v.u = ((unsigned)u) << 16;
    return v.f;
}
static __device__ __forceinline__ void unpack8(uint4 r, float* f) {
    union { unsigned u; float v; } c;
    c.u = r.x << 16;          f[0] = c.v;
    c.u = r.x & 0xffff0000u;  f[1] = c.v;
    c.u = r.y << 16;          f[2] = c.v;
    c.u = r.y & 0xffff0000u;  f[3] = c.v;
    c.u = r.z << 16;          f[4] = c.v;
    c.u = r.z & 0xffff0000u;  f[5] = c.v;
    c.u = r.w << 16;          f[6] = c.v;
    c.u = r.w & 0xffff0000u;  f[7] = c.v;
}
static __device__ __forceinline__ uint4 pack8(const float* f) {
    uint4 o;
    o.x = (unsigned)f2bf(f[0]) | ((unsigned)f2bf(f[1]) << 16);
    o.y = (unsigned)f2bf(f[2]) | ((unsigned)f2bf(f[3]) << 16);
    o.z = (unsigned)f2bf(f[4]) | ((unsigned)f2bf(f[5]) << 16);
    o.w = (unsigned)f2bf(f[6]) | ((unsigned)f2bf(f[7]) << 16);
    return o;
}

// ---------------------------------------------------------------------------
// hist+scan (one block): deg[] via LDS histogram, exclusive scan -> row_ptr,
// cnt[] zeroing.
// ---------------------------------------------------------------------------
__global__ __launch_bounds__(1024) void hist_scan_kernel(
        const int* __restrict__ ei, int* __restrict__ deg,
        int* __restrict__ row_ptr, int* __restrict__ cnt) {
    __shared__ int hist[N_NODES];        // 32 KB
    __shared__ int sums[1024];
    int t = threadIdx.x;
#pragma unroll
    for (int i = 0; i < 8; i++) hist[t + i * 1024] = 0;
    __syncthreads();
#pragma unroll
    for (int i = 0; i < 64; i++) {
        int d = ei[N_EDGES + i * 1024 + t];
        atomicAdd(&hist[d], 1);
    }
    __syncthreads();
    int base = t * 8;
    int local[8], run = 0;
#pragma unroll
    for (int i = 0; i < 8; i++) {
        int dv = hist[base + i];
        deg[base + i] = dv;
        cnt[base + i] = 0;
        local[i] = run; run += dv;
    }
    sums[t] = run;
    __syncthreads();
    for (int off = 1; off < 1024; off <<= 1) {
        int val = (t >= off) ? sums[t - off] : 0;
        __syncthreads();
        sums[t] += val;
        __syncthreads();
    }
    int offset = (t == 0) ? 0 : sums[t - 1];
#pragma unroll
    for (int i = 0; i < 8; i++) row_ptr[base + i] = offset + local[i];
    if (t == 1023) row_ptr[N_NODES] = sums[1023];
}

// ---------------------------------------------------------------------------
// megaprep: fill CSR (blocks 0..255) + xcvt (256..4351) + W1^T (4352..6399)
// + W2^T (6400..10495) + W3 bf16 cvt (10496). One launch.
// ---------------------------------------------------------------------------
static __device__ __forceinline__ void transpose_body(
        const float* __restrict__ W, unsigned short* __restrict__ Wt,
        int K, int N, int k0, int n0, int tid, float (*t)[33]) {
    int c = tid & 31, r8 = tid >> 5;
#pragma unroll
    for (int i = 0; i < 4; i++) {
        int r = r8 + i * 8;
        t[r][c] = W[(size_t)(k0 + r) * N + n0 + c];
    }
    __syncthreads();
#pragma unroll
    for (int i = 0; i < 4; i++) {
        int r = r8 + i * 8;
        Wt[(size_t)(n0 + r) * K + k0 + c] = f2bf(t[c][r]);
    }
}

__global__ __launch_bounds__(256) void megaprep_kernel(
        const int* __restrict__ ei, const int* __restrict__ deg,
        const int* __restrict__ row_ptr, int* __restrict__ cnt,
        int* __restrict__ csr_src, float* __restrict__ csr_w,
        const float* __restrict__ x, unsigned short* __restrict__ xb,
        const float* __restrict__ W1, unsigned short* __restrict__ W1t,
        const float* __restrict__ W2, unsigned short* __restrict__ W2t,
        const float* __restrict__ W3, unsigned short* __restrict__ w3b) {
    __shared__ float t[32][33];
    int b = blockIdx.x, tid = threadIdx.x;
    if (b < 256) {
        int e = b * 256 + tid;
        int s = ei[e];
        int d = ei[N_EDGES + e];
        int slot = row_ptr[d] + atomicAdd(&cnt[d], 1);
        csr_src[slot] = s;
        csr_w[slot] = rsqrtf((float)((deg[s] + 1) * (deg[d] + 1)));
    } else if (b < 4352) {
        int i = (b - 256) * 256 + tid;
        float4 a = ((const float4*)x)[i];
        ushort4 o;
        o.x = f2bf(a.x); o.y = f2bf(a.y); o.z = f2bf(a.z); o.w = f2bf(a.w);
        ((ushort4*)xb)[i] = o;
    } else if (b < 6400) {
        int bb = b - 4352;                       // W1: K=512, N=4096
        transpose_body(W1, W1t, F_IN, HID1, (bb >> 7) * 32, (bb & 127) * 32, tid, t);
    } else if (b < 10496) {
        int bb = b - 6400;                       // W2: K=4096, N=1024
        transpose_body(W2, W2t, HID1, HID2, (bb >> 5) * 32, (bb & 31) * 32, tid, t);
    } else {
        // W3 [1024,10] f32 -> w3b [10][W3B_STRIDE] bf16 (transposed)
        for (int i = tid; i < HID2 * F_OUT; i += 256) {
            int k = i / F_OUT, c = i % F_OUT;
            w3b[c * W3B_STRIDE + k] = f2bf(W3[i]);
        }
    }
}

// ---------------------------------------------------------------------------
// agg1: agg_x[v,:] = sum_e w_e*xb[src,:] + xb[v,:]/(deg+1) -> bf16
// 1 node per wave (64 lanes x uint4 = 1 KB row), 4 nodes/block. Unroll x4.
// ---------------------------------------------------------------------------
__global__ __launch_bounds__(256) void agg1_kernel(
        const unsigned short* __restrict__ xb, const int* __restrict__ row_ptr,
        const int* __restrict__ csr_src, const float* __restrict__ csr_w,
        const int* __restrict__ deg, unsigned short* __restrict__ out) {
    int v = blockIdx.x * 4 + (threadIdx.x >> 6);
    int t = threadIdx.x & 63;
    const uint4* xp = (const uint4*)xb;        // row stride 64 uint4
    float sw = 1.0f / (float)(deg[v] + 1);
    float acc[8], tmp[8];
    unpack8(xp[(size_t)v * 64 + t], tmp);
#pragma unroll
    for (int j = 0; j < 8; j++) acc[j] = sw * tmp[j];
    int e = row_ptr[v], end = row_ptr[v + 1];
    for (; e + 4 <= end; e += 4) {
        int s0 = csr_src[e], s1 = csr_src[e + 1];
        int s2 = csr_src[e + 2], s3 = csr_src[e + 3];
        float w0 = csr_w[e], w1 = csr_w[e + 1];
        float w2 = csr_w[e + 2], w3 = csr_w[e + 3];
        float f0[8], f1[8], f2[8], f3[8];
        unpack8(xp[(size_t)s0 * 64 + t], f0);
        unpack8(xp[(size_t)s1 * 64 + t], f1);
        unpack8(xp[(size_t)s2 * 64 + t], f2);
        unpack8(xp[(size_t)s3 * 64 + t], f3);
#pragma unroll
        for (int j = 0; j < 8; j++)
            acc[j] += w0 * f0[j] + w1 * f1[j] + w2 * f2[j] + w3 * f3[j];
    }
    for (; e < end; e++) {
        int s = csr_src[e];
        float w = csr_w[e];
        float f0[8];
        unpack8(xp[(size_t)s * 64 + t], f0);
#pragma unroll
        for (int j = 0; j < 8; j++) acc[j] += w * f0[j];
    }
    ((uint4*)out)[(size_t)v * 64 + t] = pack8(acc);
}

// ---------------------------------------------------------------------------
// agg2 + gemm3 fused. Unroll x4 on the edge loop.
// ---------------------------------------------------------------------------
__global__ __launch_bounds__(256) void agg2_gemm3_kernel(
        const unsigned short* __restrict__ h, const int* __restrict__ row_ptr,
        const int* __restrict__ csr_src, const float* __restrict__ csr_w,
        const int* __restrict__ deg, const float* __restrict__ b2,
        const unsigned short* __restrict__ w3b, float* __restrict__ H3) {
    __shared__ unsigned short w3s[F_OUT * W3B_STRIDE];   // ~20.2 KB
    __shared__ float red[4][F_OUT];
    int tid = threadIdx.x;
    for (int i = tid; i < F_OUT * W3B_STRIDE; i += 256) w3s[i] = w3b[i];
    __syncthreads();
    int half = tid >> 7;
    int t = tid & 127;
    int v = blockIdx.x * 2 + half;
    const uint4* hp = (const uint4*)h;   // row stride 128 uint4
    float sw = 1.0f / (float)(deg[v] + 1);
    float acc[8], tmp[8];
    unpack8(hp[(size_t)v * 128 + t], tmp);
#pragma unroll
    for (int j = 0; j < 8; j++) acc[j] = sw * tmp[j];
    int e = row_ptr[v], end = row_ptr[v + 1];
    for (; e + 4 <= end; e += 4) {
        int s0 = csr_src[e], s1 = csr_src[e + 1];
        int s2 = csr_src[e + 2], s3 = csr_src[e + 3];
        float w0 = csr_w[e], w1 = csr_w[e + 1];
        float w2 = csr_w[e + 2], w3 = csr_w[e + 3];
        float f0[8], f1[8], f2[8], f3[8];
        unpack8(hp[(size_t)s0 * 128 + t], f0);
        unpack8(hp[(size_t)s1 * 128 + t], f1);
        unpack8(hp[(size_t)s2 * 128 + t], f2);
        unpack8(hp[(size_t)s3 * 128 + t], f3);
#pragma unroll
        for (int j = 0; j < 8; j++)
            acc[j] += w0 * f0[j] + w1 * f1[j] + w2 * f2[j] + w3 * f3[j];
    }
    for (; e < end; e++) {
        int s = csr_src[e];
        float w = csr_w[e];
        float f0[8];
        unpack8(hp[(size_t)s * 128 + t], f0);
#pragma unroll
        for (int j = 0; j < 8; j++) acc[j] += w * f0[j];
    }
    float4 b4a = ((const float4*)b2)[t * 2];
    float4 b4b = ((const float4*)b2)[t * 2 + 1];
    acc[0] = fmaxf(acc[0] + b4a.x, 0.0f); acc[1] = fmaxf(acc[1] + b4a.y, 0.0f);
    acc[2] = fmaxf(acc[2] + b4a.z, 0.0f); acc[3] = fmaxf(acc[3] + b4a.w, 0.0f);
    acc[4] = fmaxf(acc[4] + b4b.x, 0.0f); acc[5] = fmaxf(acc[5] + b4b.y, 0.0f);
    acc[6] = fmaxf(acc[6] + b4b.z, 0.0f); acc[7] = fmaxf(acc[7] + b4b.w, 0.0f);

    float partial[F_OUT];
#pragma unroll
    for (int c = 0; c < F_OUT; c++) {
        float wf[8];
        unpack8(*(const uint4*)&w3s[c * W3B_STRIDE + t * 8], wf);
        partial[c] = acc[0] * wf[0] + acc[1] * wf[1] + acc[2] * wf[2] + acc[3] * wf[3]
                   + acc[4] * wf[4] + acc[5] * wf[5] + acc[6] * wf[6] + acc[7] * wf[7];
    }
#pragma unroll
    for (int c = 0; c < F_OUT; c++) {
#pragma unroll
        for (int off = 32; off > 0; off >>= 1)
            partial[c] += __shfl_xor(partial[c], off, 64);
    }
    int wave = tid >> 6, lane = tid & 63;
    if (lane == 0) {
#pragma unroll
        for (int c = 0; c < F_OUT; c++) red[wave][c] = partial[c];
    }
    __syncthreads();
    if (tid < 2 * F_OUT) {
        int hh = tid / F_OUT, c = tid % F_OUT;
        H3[(size_t)(blockIdx.x * 2 + hh) * H3_STRIDE + c] =
            red[hh * 2][c] + red[hh * 2 + 1][c];
    }
}

// ---------------------------------------------------------------------------
// GEMM2 (R11): 128x128 tile, BK=128, 32x32x16 MFMA, global_load_lds staging.
// Back to the optimal 128^2 tile; BK=128 halves barrier count (8 iters).
// LDS 64 KB -> still 2 blocks/CU (grid was already the limit at 512 blocks).
// ---------------------------------------------------------------------------
template <bool OUT_BF16, bool BIAS, bool RELU>
__global__ __launch_bounds__(256) void gemm2_mfma_kernel(
        const unsigned short* __restrict__ A,   // [M,K] bf16
        const unsigned short* __restrict__ Bt,  // [N,K] bf16
        const float* __restrict__ bias,         // [N] or null
        void* __restrict__ C,                   // [M,N] bf16 or f32
        int M, int N, int K) {
    __shared__ unsigned short As[128 * 128];    // 32 KB
    __shared__ unsigned short Bs[128 * 128];    // 32 KB
    int tid = threadIdx.x;
    int wave = tid >> 6, lane = tid & 63;
    int wm = wave >> 1, wn = wave & 1;
    int GN = N >> 7;
    int b = blockIdx.x;
    int ntile = (b >> 3) % GN;
    int mtile = ((b >> 3) / GN) * 8 + (b & 7);
    int m0 = mtile * 128, n0 = ntile * 128;
    int lrow = lane & 31, lhalf = lane >> 5;

    floatx16 acc[2][2] = {};

    for (int k0 = 0; k0 < K; k0 += 128) {
#pragma unroll
        for (int j = 0; j < 8; j++) {           // 2048 16B slots per matrix
            int idx = j * 256 + tid;
            int r = idx >> 4;                   // row 0..127
            int kc = (idx & 15) ^ (r & 15);     // XOR swizzle on source chunk
            __builtin_amdgcn_global_load_lds(
                (const __attribute__((address_space(1))) void*)(A + (size_t)(m0 + r) * K + k0 + kc * 8),
                (__attribute__((address_space(3))) void*)(&As[idx * 8]), 16, 0, 0);
            __builtin_amdgcn_global_load_lds(
                (const __attribute__((address_space(1))) void*)(Bt + (size_t)(n0 + r) * K + k0 + kc * 8),
                (__attribute__((address_space(3))) void*)(&Bs[idx * 8]), 16, 0, 0);
        }
        __syncthreads();
#pragma unroll
        for (int kk = 0; kk < 8; kk++) {        // k-16 steps
            bf16x8 af[2], bfr[2];
            int c = kk * 2 + lhalf;             // source chunk 0..15
#pragma unroll
            for (int mt = 0; mt < 2; mt++) {
                int R = wm * 64 + mt * 32 + lrow;
                af[mt] = *(const bf16x8*)&As[(R * 16 + (c ^ (R & 15))) * 8];
            }
#pragma unroll
            for (int nt = 0; nt < 2; nt++) {
                int R = wn * 64 + nt * 32 + lrow;
                bfr[nt] = *(const bf16x8*)&Bs[(R * 16 + (c ^ (R & 15))) * 8];
            }
#pragma unroll
            for (int mt = 0; mt < 2; mt++)
#pragma unroll
                for (int nt = 0; nt < 2; nt++)
                    acc[mt][nt] = __builtin_amdgcn_mfma_f32_32x32x16_bf16(
                        af[mt], bfr[nt], acc[mt][nt], 0, 0, 0);
        }
        __syncthreads();
    }

#pragma unroll
    for (int mt = 0; mt < 2; mt++) {
#pragma unroll
        for (int nt = 0; nt < 2; nt++) {
            int col = n0 + wn * 64 + nt * 32 + lrow;
            float bv = BIAS ? bias[col] : 0.0f;
#pragma unroll
            for (int reg = 0; reg < 16; reg++) {
                int row = m0 + wm * 64 + mt * 32 + (reg & 3) + 8 * (reg >> 2) + 4 * lhalf;
                float v = acc[mt][nt][reg] + bv;
                if (RELU) v = fmaxf(v, 0.0f);
                if (OUT_BF16)
                    ((unsigned short*)C)[(size_t)row * N + col] = f2bf(v);
                else
                    ((float*)C)[(size_t)row * N + col] = v;
            }
        }
    }
}

// ---------------------------------------------------------------------------
// GEMM1: 256x128 tile, BK=64, 32x32x16 MFMA (unchanged control).
// ---------------------------------------------------------------------------
__global__ __launch_bounds__(256, 2) void gemm1_mfma_kernel(
        const unsigned short* __restrict__ A,   // [8192,512] bf16
        const unsigned short* __restrict__ Bt,  // [4096,512] bf16
        const float* __restrict__ bias,         // [4096]
        unsigned short* __restrict__ C) {       // [8192,4096] bf16
    __shared__ unsigned short As[256 * 64];     // 32 KB
    __shared__ unsigned short Bs[128 * 64];     // 16 KB
    const int K = F_IN, N = HID1;
    int tid = threadIdx.x;
    int wave = tid >> 6, lane = tid & 63;
    int wm = wave >> 1, wn = wave & 1;          // 2x2 waves, wave-tile 128x64
    int b = blockIdx.x;
    int GN = N >> 7;                            // 32 n-tiles
    int ntile = (b >> 3) % GN;
    int mtile = ((b >> 3) / GN) * 8 + (b & 7);  // 0..31
    int m0 = mtile * 256, n0 = ntile * 128;
    int lrow = lane & 31, lhalf = lane >> 5;

    floatx16 acc[4][2] = {};

    for (int k0 = 0; k0 < K; k0 += 64) {
#pragma unroll
        for (int j = 0; j < 8; j++) {           // A: 2048 slots
            int idx = j * 256 + tid;
            int r = idx >> 3;                   // 0..255
            int kc = (idx & 7) ^ (r & 7);
            __builtin_amdgcn_global_load_lds(
                (const __attribute__((address_space(1))) void*)(A + (size_t)(m0 + r) * K + k0 + kc * 8),
                (__attribute__((address_space(3))) void*)(&As[idx * 8]), 16, 0, 0);
        }
#pragma unroll
        for (int j = 0; j < 4; j++) {           // B: 1024 slots
            int idx = j * 256 + tid;
            int r = idx >> 3;                   // 0..127
            int kc = (idx & 7) ^ (r & 7);
            __builtin_amdgcn_global_load_lds(
                (const __attribute__((address_space(1))) void*)(Bt + (size_t)(n0 + r) * K + k0 + kc * 8),
                (__attribute__((address_space(3))) void*)(&Bs[idx * 8]), 16, 0, 0);
        }
        __syncthreads();
#pragma unroll
        for (int kk = 0; kk < 4; kk++) {
            bf16x8 af[4], bfr[2];
            int c = kk * 2 + lhalf;
#pragma unroll
            for (int mt = 0; mt < 4; mt++) {
                int R = wm * 128 + mt * 32 + lrow;
                af[mt] = *(const bf16x8*)&As[(R * 8 + (c ^ (R & 7))) * 8];
            }
#pragma unroll
            for (int nt = 0; nt < 2; nt++) {
                int R = wn * 64 + nt * 32 + lrow;
                bfr[nt] = *(const bf16x8*)&Bs[(R * 8 + (c ^ (R & 7))) * 8];
            }
#pragma unroll
            for (int mt = 0; mt < 4; mt++)
#pragma unroll
                for (int nt = 0; nt < 2; nt++)
                    acc[mt][nt] = __builtin_amdgcn_mfma_f32_32x32x16_bf16(
                        af[mt], bfr[nt], acc[mt][nt], 0, 0, 0);
        }
        __syncthreads();
    }

#pragma unroll
    for (int mt = 0; mt < 4; mt++) {
#pragma unroll
        for (int nt = 0; nt < 2; nt++) {
            int col = n0 + wn * 64 + nt * 32 + lrow;
            float bv = bias[col];
#pragma unroll
            for (int reg = 0; reg < 16; reg++) {
                int row = m0 + wm * 128 + mt * 32 + (reg & 3) + 8 * (reg >> 2) + 4 * lhalf;
                float v = fmaxf(acc[mt][nt][reg] + bv, 0.0f);
                C[(size_t)row * N + col] = f2bf(v);
            }
        }
    }
}

// ---------------------------------------------------------------------------
// Final: aggregate h3 (stride 16), add b3, log_softmax per node.
// ---------------------------------------------------------------------------
__global__ void final_kernel(const float* __restrict__ h3, const int* __restrict__ row_ptr,
                             const int* __restrict__ csr_src, const float* __restrict__ csr_w,
                             const int* __restrict__ deg, const float* __restrict__ b3,
                             float* __restrict__ out) {
    int v = blockIdx.x * blockDim.x + threadIdx.x;
    if (v >= N_NODES) return;
    const float4* h4 = (const float4*)h3;
    float sw = 1.0f / (float)(deg[v] + 1);
    float a[12];
    *(float4*)&a[0] = h4[v * 4];
    *(float4*)&a[4] = h4[v * 4 + 1];
    *(float4*)&a[8] = h4[v * 4 + 2];
    float acc[F_OUT];
#pragma unroll
    for (int c = 0; c < F_OUT; c++) acc[c] = b3[c] + sw * a[c];
    int end = row_ptr[v + 1];
    for (int e = row_ptr[v]; e < end; e++) {
        int s = csr_src[e];
        float w = csr_w[e];
        float bsrc[12];
        *(float4*)&bsrc[0] = h4[s * 4];
        *(float4*)&bsrc[4] = h4[s * 4 + 1];
        *(float4*)&bsrc[8] = h4[s * 4 + 2];
#pragma unroll
        for (int c = 0; c < F_OUT; c++) acc[c] += w * bsrc[c];
    }
    float m = acc[0];
#pragma unroll
    for (int c = 1; c < F_OUT; c++) m = fmaxf(m, acc[c]);
    float ssum = 0.0f;
#pragma unroll
    for (int c = 0; c < F_OUT; c++) ssum += expf(acc[c] - m);
    float l = logf(ssum);
#pragma unroll
    for (int c = 0; c < F_OUT; c++) out[v * F_OUT + c] = acc[c] - m - l;
}

// ---------------------------------------------------------------------------
// Launch (7 dispatches)
// ---------------------------------------------------------------------------
extern "C" void kernel_launch(void* const* d_in, const int* in_sizes, int n_in,
                              void* d_out, int out_size, void* d_ws, size_t ws_size,
                              hipStream_t stream) {
    const float* x  = (const float*)d_in[0];
    const float* W1 = (const float*)d_in[1];
    const float* b1 = (const float*)d_in[2];
    const float* W2 = (const float*)d_in[3];
    const float* b2 = (const float*)d_in[4];
    const float* W3 = (const float*)d_in[5];
    const float* b3 = (const float*)d_in[6];
    const int*   ei = (const int*)d_in[7];
    float* out = (float*)d_out;

    char* p = (char*)d_ws;
    int*   deg     = (int*)p;    p += N_NODES * 4;
    int*   cnt     = (int*)p;    p += N_NODES * 4;
    int*   row_ptr = (int*)p;    p += 33024;
    int*   csr_src = (int*)p;    p += N_EDGES * 4;
    float* csr_w   = (float*)p;  p += N_EDGES * 4;
    float* h3      = (float*)p;  p += N_NODES * H3_STRIDE * 4;
    unsigned short* w3b = (unsigned short*)p; p += (F_OUT * W3B_STRIDE * 2 + 255) / 256 * 256;
    unsigned short* xb    = (unsigned short*)p; p += (size_t)N_NODES * F_IN * 2;
    unsigned short* agg_x = (unsigned short*)p; p += (size_t)N_NODES * F_IN * 2;
    unsigned short* W1t   = (unsigned short*)p; p += (size_t)HID1 * F_IN * 2;
    unsigned short* W2t   = (unsigned short*)p; p += (size_t)HID2 * HID1 * 2;
    unsigned short* h1    = (unsigned short*)p; p += (size_t)N_NODES * HID1 * 2;
    unsigned short* h2pre = (unsigned short*)p; p += (size_t)N_NODES * HID2 * 2;

    // Graph preprocessing + all conversions (2 launches)
    hist_scan_kernel<<<1, 1024, 0, stream>>>(ei, deg, row_ptr, cnt);
    megaprep_kernel<<<10497, 256, 0, stream>>>(ei, deg, row_ptr, cnt, csr_src, csr_w,
                                               x, xb, W1, W1t, W2, W2t, W3, w3b);

    // Layer 1
    agg1_kernel<<<N_NODES / 4, 256, 0, stream>>>(xb, row_ptr, csr_src, csr_w, deg, agg_x);
    gemm1_mfma_kernel<<<(HID1 / 128) * (N_NODES / 256), 256, 0, stream>>>(agg_x, W1t, b1, h1);

    // Layer 2 (128x128 tile, BK=128: half the barriers at same occupancy)
    gemm2_mfma_kernel<true, false, false><<<(HID2 / 128) * (N_NODES / 128), 256, 0, stream>>>(
        h1, W2t, nullptr, h2pre, N_NODES, HID2, HID1);

    // Layer 2 aggregation + Layer 3 GEMM fused
    agg2_gemm3_kernel<<<N_NODES / 2, 256, 0, stream>>>(h2pre, row_ptr, csr_src, csr_w,
                                                       deg, b2, w3b, h3);

    // Output
    final_kernel<<<N_NODES / 256, 256, 0, stream>>>(h3, row_ptr, csr_src, csr_w, deg, b3, out);
}